// Round 13
// baseline (130.721 us; speedup 1.0000x reference)
//
#include <hip/hip_runtime.h>
#include <math.h>

namespace {

constexpr int B = 16, H = 512, W = 512;
constexpr int HWc = H * W;                 // 262144
constexpr size_t Nc = (size_t)B * HWc;     // 4194304

// Strip geometry: 64-lane wave holds cols [strip*42-11, strip*42+52].
// Boundary stencil (3x3) corrupts lanes 0,63; each of the 10 dilation steps
// corrupts one more lane per side -> valid central lanes 11..52 = 42 cols.
// 13 strips x 42 = 546 >= 512 (mask col < 512). Exact tiling, no overlap.
constexpr int NSTRIP = 13;
constexpr int CENT = 42;
constexpr int NBAND = 16;  // 512 / 32 rows
constexpr int NWORK = NSTRIP * NBAND * B * 2;  // 6656 chain_p slots (layout)
constexpr int NMERGED = NSTRIP * NBAND * B;    // 3328 merged wave work items
constexpr int NSB = NMERGED / 4;               // 832 stencil blocks
constexpr int NBCE = B * 64;                   // 1024 bce blocks

// R13: chains MERGED into one wave per (img,band,strip). R12's two waves per
// cell each built the float pred-boundary independently (chain-1's o[] was
// instruction-identical to chain-0's a[10..41]). One wave now: build float
// a[52] once; bit cascade FIRST (accumulates |bit - a[10+k]| against
// pristine a); extract bit-boundary as o0[32] floats; float cascade against
// o0. Halves wave count, eliminates one 34-row sigmoid boundary build +
// duplicate loads. Peak live set unchanged (~a[52]+o[32]) -> same VGPR=60
// allocation class.

// ---------------- DPP lane shifts ----------------
// wave_shr:1 (0x138): lane i <- lane i-1 (lane 0 keeps own -> replicate edge)
// wave_shl:1 (0x130): lane i <- lane i+1 (lane 63 keeps own)
template <int CTRL>
__device__ __forceinline__ float dpp_shift1(float v) {
  int i = __float_as_int(v);
  int r = __builtin_amdgcn_update_dpp(i, i, CTRL, 0xF, 0xF, false);
  return __int_as_float(r);
}
template <int CTRL>
__device__ __forceinline__ unsigned dpp_shift1u(unsigned v) {
  return (unsigned)__builtin_amdgcn_update_dpp((int)v, (int)v, CTRL, 0xF, 0xF,
                                               false);
}

// R5: NO inline-asm max3 (pins live set to VGPR half -> spill). R8: NO
// __launch_bounds__ loosening ((256,3) chose spill over AGPR split).
__device__ __forceinline__ float hmax3(float v) {
  return fmaxf(fmaxf(dpp_shift1<0x138>(v), v), dpp_shift1<0x130>(v));
}
__device__ __forceinline__ void hminmax3(float v, float& mx, float& mn) {
  float s1 = dpp_shift1<0x138>(v);
  float s2 = dpp_shift1<0x130>(v);
  mx = fmaxf(fmaxf(s1, v), s2);
  mn = fminf(fminf(s1, v), s2);
}

// Bitwise horizontal 3-lane OR/AND on a packed-rows u64 (per-32b half; DPP
// replicates at wave edges -- identical halo geometry to the float path).
__device__ __forceinline__ unsigned long long or3_lanes(unsigned long long v) {
  unsigned lo = (unsigned)v, hi = (unsigned)(v >> 32);
  unsigned rlo = dpp_shift1u<0x138>(lo) | lo | dpp_shift1u<0x130>(lo);
  unsigned rhi = dpp_shift1u<0x138>(hi) | hi | dpp_shift1u<0x130>(hi);
  return ((unsigned long long)rhi << 32) | rlo;
}
__device__ __forceinline__ unsigned long long and3_lanes(unsigned long long v) {
  unsigned lo = (unsigned)v, hi = (unsigned)(v >> 32);
  unsigned rlo = dpp_shift1u<0x138>(lo) & lo & dpp_shift1u<0x130>(lo);
  unsigned rhi = dpp_shift1u<0x138>(hi) & hi & dpp_shift1u<0x130>(hi);
  return ((unsigned long long)rhi << 32) | rlo;
}

__device__ __forceinline__ float wave_sum(float v) {
#pragma unroll
  for (int off = 32; off > 0; off >>= 1) v += __shfl_down(v, off);
  return v;
}

// --- block-wide sum over 256 threads (4 waves of 64). Valid on tid==0 only.
__device__ __forceinline__ float block_reduce_256(float v, float* sm, int tid) {
#pragma unroll
  for (int off = 32; off > 0; off >>= 1) v += __shfl_down(v, off);
  int lane = tid & 63, wid = tid >> 6;
  if (lane == 0) sm[wid] = v;
  __syncthreads();
  float r = 0.f;
  if (tid == 0) r = sm[0] + sm[1] + sm[2] + sm[3];
  __syncthreads();
  return r;
}

__device__ __forceinline__ float sigmoid_at(const float* __restrict__ Lg,
                                            int gy, int colc) {
  gy = min(max(gy, 0), H - 1);  // wave-uniform clamp
  float x = Lg[gy * W + colc];
  float e = __expf(-x);
  return __builtin_amdgcn_rcpf(1.f + e);
}

// ---- float dilation steps via template recursion (R2: compile-time D keeps
// indices constant -> arrays register-resident). R4: accv[4] breaks the
// 320-deep dependent FMA chain.
template <int D>
__device__ __forceinline__ void dilate_steps(float (&a)[52],
                                             const float (&o)[32],
                                             float (&accv)[4]) {
  if constexpr (D <= 10) {
    float hp = hmax3(a[D - 1]);
    float hc = hmax3(a[D]);
#pragma unroll
    for (int r = D; r <= 51 - D; ++r) {  // trip count 52-2D: compile-time
      float hn = hmax3(a[r + 1]);
      float nv = fmaxf(fmaxf(hp, hc), hn);
      hp = hc;
      hc = hn;
      a[r] = nv;
    }
    constexpr float wd = 0.1f * (float)D;
#pragma unroll
    for (int k = 0; k < 32; ++k) accv[k & 3] += wd * fabsf(a[10 + k] - o[k]);
    dilate_steps<D + 1>(a, o, accv);
  }
}

// ---------------- merged stencil wave body ----------------------------------
__device__ __forceinline__ void fused_body(const float* __restrict__ Lg,
                                           const int* __restrict__ Tg,
                                           int lane, int strip, int band,
                                           int img,
                                           float* __restrict__ chain_p) {
  int col = strip * CENT - 11 + lane;
  int colc = min(max(col, 0), W - 1);
  int y0 = band * 32;

  // ---- (1) float pred-boundary incl. vertical halo: rows y0-10 .. y0+41
  float a[52];
  {
    float v0 = sigmoid_at(Lg, y0 - 11, colc);
    float v1 = sigmoid_at(Lg, y0 - 10, colc);
    float hx0, hn0, hx1, hn1;
    hminmax3(v0, hx0, hn0);
    hminmax3(v1, hx1, hn1);
#pragma unroll
    for (int r = 0; r < 52; ++r) {
      float v2 = sigmoid_at(Lg, y0 - 9 + r, colc);
      float hx2, hn2;
      hminmax3(v2, hx2, hn2);
      a[r] = fmaxf(fmaxf(hx0, hx1), hx2) - fminf(fminf(hn0, hn1), hn2);
      hx0 = hx1;
      hx1 = hx2;
      hn0 = hn1;
      hn1 = hn2;
    }
  }

  // ---- (2) packed target bits + bitwise gt-boundary (R12-proven)
  unsigned long long ab0;
  {
    unsigned long long tb = 0ull;
#pragma unroll
    for (int j = 0; j < 54; ++j) {
      int gy = min(max(y0 - 11 + j, 0), H - 1);
      tb |= (unsigned long long)(unsigned)Tg[gy * W + colc] << j;
    }
    unsigned long long vd = tb | (tb << 1) | (tb >> 1);
    unsigned long long ve = tb & (tb << 1) & (tb >> 1);
    ab0 = (or3_lanes(vd) & ~and3_lanes(ve)) >> 1;  // bit r = row y0-10+r
  }

  // ---- (3) bit cascade FIRST: accumulates |gt_dil_d - pred_b| against the
  // PRISTINE a (a[10+k] == chain-1's old o[k], instruction-identical).
  float accv1[4] = {0.f, 0.f, 0.f, 0.f};
  {
    unsigned long long ab = ab0;
#pragma unroll
    for (int d = 1; d <= 10; ++d) {
      unsigned long long s = ab | (ab << 1) | (ab >> 1);
      ab = or3_lanes(s);
      const float wd = 0.1f * (float)d;
      unsigned lo = (unsigned)ab, hi = (unsigned)(ab >> 32);
#pragma unroll
      for (int k = 0; k < 32; ++k) {
        // row 10+k: bits 10..31 in lo (k<22), bits 0..9 in hi (k>=22)
        unsigned bit =
            (k < 22) ? ((lo >> (10 + k)) & 1u) : ((hi >> (k - 22)) & 1u);
        accv1[k & 3] += wd * fabsf((float)bit - a[10 + k]);
      }
    }
  }
  float acc1 = (accv1[0] + accv1[1]) + (accv1[2] + accv1[3]);

  // ---- (4) extract gt-boundary central rows as floats (chain-0's o[])
  float o0[32];
  {
    unsigned lo = (unsigned)ab0, hi = (unsigned)(ab0 >> 32);
#pragma unroll
    for (int k = 0; k < 32; ++k) {
      unsigned bit =
          (k < 22) ? ((lo >> (10 + k)) & 1u) : ((hi >> (k - 22)) & 1u);
      o0[k] = (float)bit;
    }
  }

  // ---- (5) float cascade: |pred_dil_d - gt_b| (mutates a; bits now dead)
  float accv0[4] = {0.f, 0.f, 0.f, 0.f};
  dilate_steps<1>(a, o0, accv0);
  float acc0 = (accv0[0] + accv0[1]) + (accv0[2] + accv0[3]);

  bool valid = (lane >= 11 && lane <= 52 && col < W);
  acc0 = valid ? acc0 : 0.f;
  acc1 = valid ? acc1 : 0.f;
  acc0 = wave_sum(acc0);
  acc1 = wave_sum(acc1);
  if (lane == 0) {
    chain_p[(img * NBAND + band) * NSTRIP + strip] = acc0;           // chain 0
    chain_p[((16 + img) * NBAND + band) * NSTRIP + strip] = acc1;    // chain 1
  }
}

// ---------------- BCE block body (R7-proven) --------------------------------
// Identity: max(x,0) - x*t + log1p(exp(-|x|)) == x*(1-t) + log(1+e^-x).
__device__ __forceinline__ void bce_body(const float* __restrict__ logits,
                                         const int* __restrict__ target,
                                         int blk, float* __restrict__ bceA,
                                         float* __restrict__ spA,
                                         float* __restrict__ stA,
                                         float* __restrict__ sptA, float* sm) {
  int img = blk >> 6, seg = blk & 63;  // 64 blocks/image
  const float4* L4 =
      (const float4*)(logits + (size_t)img * HWc + (size_t)seg * 4096);
  const int4* T4 =
      (const int4*)(target + (size_t)img * HWc + (size_t)seg * 4096);
  int tid = threadIdx.x;
  float s_bce = 0.f, s_p = 0.f, s_t = 0.f, s_pt = 0.f;
#pragma unroll
  for (int it = 0; it < 4; ++it) {
    float4 x4 = L4[it * 256 + tid];
    int4 t4 = T4[it * 256 + tid];
    float xs[4] = {x4.x, x4.y, x4.z, x4.w};
    int ts[4] = {t4.x, t4.y, t4.z, t4.w};
#pragma unroll
    for (int j = 0; j < 4; ++j) {
      float x = xs[j];
      float tf = (float)ts[j];
      float e = __expf(-x);
      float p = __builtin_amdgcn_rcpf(1.f + e);
      s_p += p;
      s_t += tf;
      s_pt += p * tf;
      s_bce += x * (1.f - tf) + __logf(1.f + e);
    }
  }
  float r;
  r = block_reduce_256(s_bce, sm, tid);
  if (tid == 0) bceA[blk] = r;
  r = block_reduce_256(s_p, sm, tid);
  if (tid == 0) spA[blk] = r;
  r = block_reduce_256(s_t, sm, tid);
  if (tid == 0) stA[blk] = r;
  r = block_reduce_256(s_pt, sm, tid);
  if (tid == 0) sptA[blk] = r;
}

// ---------------- merged kernel (R7-proven structure) -----------------------
// Heterogeneous blocks: first NBCE blocks stream BCE/dice partials (memory-
// bound), remaining NSB blocks run the merged stencil (VALU-bound), 4
// independent waves each. __launch_bounds__(256, 4): the ONLY proven shape.
__global__ void __launch_bounds__(256, 4) fused_kernel(
    const float* __restrict__ logits, const int* __restrict__ target,
    float* __restrict__ bceA, float* __restrict__ spA,
    float* __restrict__ stA, float* __restrict__ sptA,
    float* __restrict__ chain_p) {
  __shared__ float smr[4];
  int tid = threadIdx.x;
  if (blockIdx.x < NBCE) {
    bce_body(logits, target, blockIdx.x, bceA, spA, stA, sptA, smr);
    return;
  }
  int lane = tid & 63;
  int wv = __builtin_amdgcn_readfirstlane(tid >> 6);
  int widx = (blockIdx.x - NBCE) * 4 + wv;  // 0..3327, exact
  int strip = widx % NSTRIP;
  int rest = widx / NSTRIP;  // 0..255
  int band = rest & 15;
  int img = rest >> 4;       // 0..15
  const float* Lg = logits + (size_t)img * HWc;
  const int* Tg = target + (size_t)img * HWc;
  fused_body(Lg, Tg, lane, strip, band, img, chain_p);
}

// ---------------- finalize (R12) --------------------------------------------
__global__ void finalize_kernel(const float* __restrict__ bceA,
                                const float* __restrict__ spA,
                                const float* __restrict__ stA,
                                const float* __restrict__ sptA,
                                const float* __restrict__ chain_p,
                                float* __restrict__ out) {
  __shared__ float smr[4];
  __shared__ float smImg[16][3];
  __shared__ double smd[16][2];
  int tid = threadIdx.x;

  float s = 0.f;
  {
    const float4* b4 = (const float4*)bceA;  // 256 float4s
    for (int i = tid; i < NBCE / 4; i += 256) {
      float4 v = b4[i];
      s += (v.x + v.y) + (v.z + v.w);
    }
  }
  float bce_sum = block_reduce_256(s, smr, tid);

  s = 0.f;
  {
    const float4* c4 = (const float4*)chain_p;  // 1664 float4s
    for (int i = tid; i < NWORK / 4; i += 256) {
      float4 v = c4[i];
      s += (v.x + v.y) + (v.z + v.w);
    }
  }
  float hd_sum = block_reduce_256(s, smr, tid);

  {
    int img = tid >> 4, part = tid & 15;  // 16 threads per image
    float sp = 0.f, st = 0.f, spt = 0.f;
    for (int j = part; j < 64; j += 16) {  // 64 partials/image, 4 iters
      int idx = img * 64 + j;
      sp += spA[idx];
      st += stA[idx];
      spt += sptA[idx];
    }
#pragma unroll
    for (int off = 8; off > 0; off >>= 1) {
      sp += __shfl_down(sp, off, 16);
      st += __shfl_down(st, off, 16);
      spt += __shfl_down(spt, off, 16);
    }
    if (part == 0) {
      smImg[img][0] = sp;
      smImg[img][1] = st;
      smImg[img][2] = spt;
    }
  }
  __syncthreads();
  if (tid < 16) {
    double sp = smImg[tid][0], st = smImg[tid][1], spt = smImg[tid][2];
    double dice = (2.0 * spt + 1e-6) / (sp + st + 1e-6 + 1e-7);
    double tv = (spt + 1e-6) /
                (spt + 0.7 * (sp - spt) + 0.3 * (st - spt) + 1e-6 + 1e-7);
    smd[tid][0] = 1.0 - dice;
    smd[tid][1] = pow(1.0 - tv, 0.75);
  }
  __syncthreads();
  if (tid == 0) {
    double dice_l = 0.0, ft_l = 0.0;
    for (int i = 0; i < 16; ++i) {
      dice_l += smd[i][0];
      ft_l += smd[i][1];
    }
    dice_l /= 16.0;
    ft_l /= 16.0;
    const double Nd = (double)Nc;
    double bce = (double)bce_sum / Nd;
    double hd = ((double)hd_sum / Nd) / (5.5 + 1e-8);
    out[0] = (float)(bce + dice_l + ft_l + 0.1 * hd);
  }
}

}  // namespace

extern "C" void kernel_launch(void* const* d_in, const int* in_sizes, int n_in,
                              void* d_out, int out_size, void* d_ws,
                              size_t ws_size, hipStream_t stream) {
  const float* logits = (const float*)d_in[0];
  const int* target = (const int*)d_in[1];
  float* out = (float*)d_out;

  // Workspace: only small partial arrays (boundary maps never hit global).
  // All slots below are fully written each launch.
  float* part = (float*)d_ws;
  float* bceA = part;                  // 1024
  float* spA = part + NBCE;            // 1024
  float* stA = part + 2 * NBCE;        // 1024
  float* sptA = part + 3 * NBCE;       // 1024
  float* chain_p = part + 4 * NBCE;    // 6656 = 32*16*13 (16B aligned)

  fused_kernel<<<dim3(NBCE + NSB), dim3(256), 0, stream>>>(
      logits, target, bceA, spA, stA, sptA, chain_p);
  finalize_kernel<<<1, 256, 0, stream>>>(bceA, spA, stA, sptA, chain_p, out);
}

// Round 14
// 114.310 us; speedup vs baseline: 1.1436x; 1.1436x over previous
//
#include <hip/hip_runtime.h>
#include <math.h>

namespace {

constexpr int B = 16, H = 512, W = 512;
constexpr int HWc = H * W;                 // 262144
constexpr size_t Nc = (size_t)B * HWc;     // 4194304

// Strip geometry: 64-lane wave holds cols [strip*42-11, strip*42+52].
// Boundary stencil (3x3) corrupts lanes 0,63; each of the 10 dilation steps
// corrupts one more lane per side -> valid central lanes 11..52 = 42 cols.
// 13 strips x 42 = 546 >= 512 (mask col < 512). Exact tiling, no overlap.
constexpr int NSTRIP = 13;
constexpr int CENT = 42;
constexpr int NBAND = 16;  // 512 / 32 rows
constexpr int NWORK = NSTRIP * NBAND * B * 2;  // 6656 wave work items
constexpr int NSB = NWORK / 4;                 // 1664 stencil blocks
constexpr int NBCE = B * 64;                   // 1024 bce blocks

// R13 post-mortem: merging the two chains into one wave halved stencil TLP
// for only ~12% instruction savings -> VALUBusy 70->51%, fused 51->64us.
// REVERTED to R12's two-wave-per-cell structure (TLP is load-bearing).
// This file = R12 + SWAR-counted chain-1 accumulate (below).

// ---------------- DPP lane shifts ----------------
// wave_shr:1 (0x138): lane i <- lane i-1 (lane 0 keeps own -> replicate edge)
// wave_shl:1 (0x130): lane i <- lane i+1 (lane 63 keeps own)
template <int CTRL>
__device__ __forceinline__ float dpp_shift1(float v) {
  int i = __float_as_int(v);
  int r = __builtin_amdgcn_update_dpp(i, i, CTRL, 0xF, 0xF, false);
  return __int_as_float(r);
}
template <int CTRL>
__device__ __forceinline__ unsigned dpp_shift1u(unsigned v) {
  return (unsigned)__builtin_amdgcn_update_dpp((int)v, (int)v, CTRL, 0xF, 0xF,
                                               false);
}

// R5: NO inline-asm max3 (pins live set to VGPR half -> spill). R8: NO
// __launch_bounds__ loosening ((256,3) chose spill over AGPR split).
__device__ __forceinline__ float hmax3(float v) {
  return fmaxf(fmaxf(dpp_shift1<0x138>(v), v), dpp_shift1<0x130>(v));
}
__device__ __forceinline__ void hminmax3(float v, float& mx, float& mn) {
  float s1 = dpp_shift1<0x138>(v);
  float s2 = dpp_shift1<0x130>(v);
  mx = fmaxf(fmaxf(s1, v), s2);
  mn = fminf(fminf(s1, v), s2);
}

// Bitwise horizontal 3-lane OR/AND on a packed-rows u64 (per-32b half; DPP
// replicates at wave edges -- identical halo geometry to the float path).
__device__ __forceinline__ unsigned long long or3_lanes(unsigned long long v) {
  unsigned lo = (unsigned)v, hi = (unsigned)(v >> 32);
  unsigned rlo = dpp_shift1u<0x138>(lo) | lo | dpp_shift1u<0x130>(lo);
  unsigned rhi = dpp_shift1u<0x138>(hi) | hi | dpp_shift1u<0x130>(hi);
  return ((unsigned long long)rhi << 32) | rlo;
}
__device__ __forceinline__ unsigned long long and3_lanes(unsigned long long v) {
  unsigned lo = (unsigned)v, hi = (unsigned)(v >> 32);
  unsigned rlo = dpp_shift1u<0x138>(lo) & lo & dpp_shift1u<0x130>(lo);
  unsigned rhi = dpp_shift1u<0x138>(hi) & hi & dpp_shift1u<0x130>(hi);
  return ((unsigned long long)rhi << 32) | rlo;
}

__device__ __forceinline__ float wave_sum(float v) {
#pragma unroll
  for (int off = 32; off > 0; off >>= 1) v += __shfl_down(v, off);
  return v;
}

// --- block-wide sum over 256 threads (4 waves of 64). Valid on tid==0 only.
__device__ __forceinline__ float block_reduce_256(float v, float* sm, int tid) {
#pragma unroll
  for (int off = 32; off > 0; off >>= 1) v += __shfl_down(v, off);
  int lane = tid & 63, wid = tid >> 6;
  if (lane == 0) sm[wid] = v;
  __syncthreads();
  float r = 0.f;
  if (tid == 0) r = sm[0] + sm[1] + sm[2] + sm[3];
  __syncthreads();
  return r;
}

// CH==0: src map = sigmoid(logits), oth map = target.
// CH==1: src map = target,          oth map = sigmoid(logits).
template <int CH>
__device__ __forceinline__ float load_src(const float* __restrict__ Lg,
                                          const int* __restrict__ Tg, int gy,
                                          int colc) {
  gy = min(max(gy, 0), H - 1);  // wave-uniform clamp
  if constexpr (CH == 0) {
    float x = Lg[gy * W + colc];
    float e = __expf(-x);
    return __builtin_amdgcn_rcpf(1.f + e);
  } else {
    return (float)Tg[gy * W + colc];
  }
}

// ---- dilation steps via template recursion (R2: compile-time D keeps all
// indices constant -> arrays stay register-resident).
// R4: accv[4] -- single acc was a 320-deep dependent FMA chain.
template <int D>
__device__ __forceinline__ void dilate_steps(float (&a)[52],
                                             const float (&o)[32],
                                             float (&accv)[4]) {
  if constexpr (D <= 10) {
    float hp = hmax3(a[D - 1]);
    float hc = hmax3(a[D]);
#pragma unroll
    for (int r = D; r <= 51 - D; ++r) {  // trip count 52-2D: compile-time
      float hn = hmax3(a[r + 1]);
      float nv = fmaxf(fmaxf(hp, hc), hn);
      hp = hc;
      hc = hn;
      a[r] = nv;
    }
    constexpr float wd = 0.1f * (float)D;
#pragma unroll
    for (int k = 0; k < 32; ++k) accv[k & 3] += wd * fabsf(a[10 + k] - o[k]);
    dilate_steps<D + 1>(a, o, accv);
  }
}

// ---------------- chain-0 wave body (R12-proven, untouched) -----------------
// src = sigmoid(logits) (continuous -> float DPP cascade), oth = target.
__device__ __forceinline__ void fused_body0(const float* __restrict__ Lg,
                                            const int* __restrict__ Tg,
                                            int lane, int strip, int band,
                                            int bz,
                                            float* __restrict__ chain_p) {
  int col = strip * CENT - 11 + lane;
  int colc = min(max(col, 0), W - 1);
  int y0 = band * 32;

  // ---- other-map boundary (target), central rows y0..y0+31
  float o[32];
  {
    float v0 = load_src<1>(Lg, Tg, y0 - 1, colc);
    float v1 = load_src<1>(Lg, Tg, y0, colc);
    float hx0, hn0, hx1, hn1;
    hminmax3(v0, hx0, hn0);
    hminmax3(v1, hx1, hn1);
#pragma unroll
    for (int k = 0; k < 32; ++k) {
      float v2 = load_src<1>(Lg, Tg, y0 + 1 + k, colc);
      float hx2, hn2;
      hminmax3(v2, hx2, hn2);
      o[k] = fmaxf(fmaxf(hx0, hx1), hx2) - fminf(fminf(hn0, hn1), hn2);
      hx0 = hx1;
      hx1 = hx2;
      hn0 = hn1;
      hn1 = hn2;
    }
  }

  // ---- src-map boundary incl. vertical halo: rows y0-10 .. y0+41
  float a[52];
  {
    float v0 = load_src<0>(Lg, Tg, y0 - 11, colc);
    float v1 = load_src<0>(Lg, Tg, y0 - 10, colc);
    float hx0, hn0, hx1, hn1;
    hminmax3(v0, hx0, hn0);
    hminmax3(v1, hx1, hn1);
#pragma unroll
    for (int r = 0; r < 52; ++r) {
      float v2 = load_src<0>(Lg, Tg, y0 - 9 + r, colc);
      float hx2, hn2;
      hminmax3(v2, hx2, hn2);
      a[r] = fmaxf(fmaxf(hx0, hx1), hx2) - fminf(fminf(hn0, hn1), hn2);
      hx0 = hx1;
      hx1 = hx2;
      hn0 = hn1;
      hn1 = hn2;
    }
  }

  float accv[4] = {0.f, 0.f, 0.f, 0.f};
  dilate_steps<1>(a, o, accv);
  float acc = (accv[0] + accv[1]) + (accv[2] + accv[3]);

  bool valid = (lane >= 11 && lane <= 52 && col < W);
  acc = valid ? acc : 0.f;
  acc = wave_sum(acc);
  if (lane == 0) chain_p[(bz * NBAND + band) * NSTRIP + strip] = acc;
}

// ---------------- chain-1 wave body: bitwise cascade + SWAR count -----------
// src = target (binary): max = OR. R12's per-d extract+FMA accumulate
// (~1.4k instr) is replaced by a closed form exploiting MONOTONICITY of bit
// dilation (b_d once set stays set): per element, with c = #steps set and
// S(c) = sum_{d >= d*} w_d = 0.05*c*(21-c)  [d* = 11-c],
//   sum_d w_d * |b_d - o| = S + o*(5.5 - 2S).
// c for all 64 rows at once via SWAR half-adder planes (4 x u64, 10 adds).
// Checks: c=0 -> 5.5*o; c=10 -> 5.5*(1-o); c=1 -> w10 = 1.0.
__device__ __forceinline__ void fused_body1(const float* __restrict__ Lg,
                                            const int* __restrict__ Tg,
                                            int lane, int strip, int band,
                                            int bz,
                                            float* __restrict__ chain_p) {
  int col = strip * CENT - 11 + lane;
  int colc = min(max(col, 0), W - 1);
  int y0 = band * 32;

  // ---- other-map boundary (sigmoid of logits), central rows y0..y0+31
  float o[32];
  {
    float v0 = load_src<0>(Lg, Tg, y0 - 1, colc);
    float v1 = load_src<0>(Lg, Tg, y0, colc);
    float hx0, hn0, hx1, hn1;
    hminmax3(v0, hx0, hn0);
    hminmax3(v1, hx1, hn1);
#pragma unroll
    for (int k = 0; k < 32; ++k) {
      float v2 = load_src<0>(Lg, Tg, y0 + 1 + k, colc);
      float hx2, hn2;
      hminmax3(v2, hx2, hn2);
      o[k] = fmaxf(fmaxf(hx0, hx1), hx2) - fminf(fminf(hn0, hn1), hn2);
      hx0 = hx1;
      hx1 = hx2;
      hn0 = hn1;
      hn1 = hn2;
    }
  }

  // ---- pack 54 target rows into bits (clamped rows inherit replicate edge)
  unsigned long long tb = 0ull;
#pragma unroll
  for (int j = 0; j < 54; ++j) {
    int gy = min(max(y0 - 11 + j, 0), H - 1);
    tb |= (unsigned long long)(unsigned)Tg[gy * W + colc] << j;
  }

  // ---- 3x3 boundary: dil & ~ero; align so bit r = boundary at row y0-10+r
  unsigned long long vd = tb | (tb << 1) | (tb >> 1);
  unsigned long long ve = tb & (tb << 1) & (tb >> 1);
  unsigned long long ab = (or3_lanes(vd) & ~and3_lanes(ve)) >> 1;

  // ---- 10-step bitwise dilation, counting set-steps per row (SWAR planes)
  unsigned long long p0 = 0ull, p1 = 0ull, p2 = 0ull, p3 = 0ull;
#pragma unroll
  for (int d = 1; d <= 10; ++d) {
    unsigned long long s = ab | (ab << 1) | (ab >> 1);
    ab = or3_lanes(s);
    unsigned long long carry = ab, t;
    t = p0 & carry;
    p0 ^= carry;
    carry = t;
    t = p1 & carry;
    p1 ^= carry;
    carry = t;
    t = p2 & carry;
    p2 ^= carry;
    carry = t;
    p3 ^= carry;  // max count 10 < 16: no overflow
  }

  // ---- closed-form weighted L1 accumulation per central row
  float accv[4] = {0.f, 0.f, 0.f, 0.f};
  {
    unsigned l0 = (unsigned)p0, h0 = (unsigned)(p0 >> 32);
    unsigned l1 = (unsigned)p1, h1 = (unsigned)(p1 >> 32);
    unsigned l2 = (unsigned)p2, h2 = (unsigned)(p2 >> 32);
    unsigned l3 = (unsigned)p3, h3 = (unsigned)(p3 >> 32);
#pragma unroll
    for (int k = 0; k < 32; ++k) {
      // row 10+k: bits 10..31 in lo (k<22), bits 0..9 in hi (k>=22)
      unsigned c;
      if (k < 22) {
        const int i = 10 + k;
        c = ((l0 >> i) & 1u) | (((l1 >> i) & 1u) << 1) |
            (((l2 >> i) & 1u) << 2) | (((l3 >> i) & 1u) << 3);
      } else {
        const int i = k - 22;
        c = ((h0 >> i) & 1u) | (((h1 >> i) & 1u) << 1) |
            (((h2 >> i) & 1u) << 2) | (((h3 >> i) & 1u) << 3);
      }
      float cf = (float)c;
      float S = 0.05f * cf * (21.f - cf);
      accv[k & 3] += S + o[k] * (5.5f - 2.f * S);
    }
  }
  float acc = (accv[0] + accv[1]) + (accv[2] + accv[3]);

  bool valid = (lane >= 11 && lane <= 52 && col < W);
  acc = valid ? acc : 0.f;
  acc = wave_sum(acc);
  if (lane == 0) chain_p[(bz * NBAND + band) * NSTRIP + strip] = acc;
}

// ---------------- BCE block body (R7-proven) --------------------------------
// Identity: max(x,0) - x*t + log1p(exp(-|x|)) == x*(1-t) + log(1+e^-x).
__device__ __forceinline__ void bce_body(const float* __restrict__ logits,
                                         const int* __restrict__ target,
                                         int blk, float* __restrict__ bceA,
                                         float* __restrict__ spA,
                                         float* __restrict__ stA,
                                         float* __restrict__ sptA, float* sm) {
  int img = blk >> 6, seg = blk & 63;  // 64 blocks/image
  const float4* L4 =
      (const float4*)(logits + (size_t)img * HWc + (size_t)seg * 4096);
  const int4* T4 =
      (const int4*)(target + (size_t)img * HWc + (size_t)seg * 4096);
  int tid = threadIdx.x;
  float s_bce = 0.f, s_p = 0.f, s_t = 0.f, s_pt = 0.f;
#pragma unroll
  for (int it = 0; it < 4; ++it) {
    float4 x4 = L4[it * 256 + tid];
    int4 t4 = T4[it * 256 + tid];
    float xs[4] = {x4.x, x4.y, x4.z, x4.w};
    int ts[4] = {t4.x, t4.y, t4.z, t4.w};
#pragma unroll
    for (int j = 0; j < 4; ++j) {
      float x = xs[j];
      float tf = (float)ts[j];
      float e = __expf(-x);
      float p = __builtin_amdgcn_rcpf(1.f + e);
      s_p += p;
      s_t += tf;
      s_pt += p * tf;
      s_bce += x * (1.f - tf) + __logf(1.f + e);
    }
  }
  float r;
  r = block_reduce_256(s_bce, sm, tid);
  if (tid == 0) bceA[blk] = r;
  r = block_reduce_256(s_p, sm, tid);
  if (tid == 0) spA[blk] = r;
  r = block_reduce_256(s_t, sm, tid);
  if (tid == 0) stA[blk] = r;
  r = block_reduce_256(s_pt, sm, tid);
  if (tid == 0) sptA[blk] = r;
}

// ---------------- merged kernel (R7/R12-proven structure) -------------------
// Heterogeneous blocks: first NBCE blocks stream BCE/dice partials (memory-
// bound), remaining NSB blocks run the stencil (VALU-bound), 4 independent
// waves each. __launch_bounds__(256, 4): the ONLY proven shape.
__global__ void __launch_bounds__(256, 4) fused_kernel(
    const float* __restrict__ logits, const int* __restrict__ target,
    float* __restrict__ bceA, float* __restrict__ spA,
    float* __restrict__ stA, float* __restrict__ sptA,
    float* __restrict__ chain_p) {
  __shared__ float smr[4];
  int tid = threadIdx.x;
  if (blockIdx.x < NBCE) {
    bce_body(logits, target, blockIdx.x, bceA, spA, stA, sptA, smr);
    return;
  }
  int lane = tid & 63;
  int wv = __builtin_amdgcn_readfirstlane(tid >> 6);
  int widx = (blockIdx.x - NBCE) * 4 + wv;  // 0..6655, exact
  int strip = widx % NSTRIP;
  int rest = widx / NSTRIP;
  int band = rest & 15;
  int bz = rest >> 4;  // 0..31
  int img = bz & 15, chain = bz >> 4;
  const float* Lg = logits + (size_t)img * HWc;
  const int* Tg = target + (size_t)img * HWc;
  if (chain == 0)
    fused_body0(Lg, Tg, lane, strip, band, bz, chain_p);
  else
    fused_body1(Lg, Tg, lane, strip, band, bz, chain_p);
}

// ---------------- finalize (R12) --------------------------------------------
__global__ void finalize_kernel(const float* __restrict__ bceA,
                                const float* __restrict__ spA,
                                const float* __restrict__ stA,
                                const float* __restrict__ sptA,
                                const float* __restrict__ chain_p,
                                float* __restrict__ out) {
  __shared__ float smr[4];
  __shared__ float smImg[16][3];
  __shared__ double smd[16][2];
  int tid = threadIdx.x;

  float s = 0.f;
  {
    const float4* b4 = (const float4*)bceA;  // 256 float4s
    for (int i = tid; i < NBCE / 4; i += 256) {
      float4 v = b4[i];
      s += (v.x + v.y) + (v.z + v.w);
    }
  }
  float bce_sum = block_reduce_256(s, smr, tid);

  s = 0.f;
  {
    const float4* c4 = (const float4*)chain_p;  // 1664 float4s
    for (int i = tid; i < NWORK / 4; i += 256) {
      float4 v = c4[i];
      s += (v.x + v.y) + (v.z + v.w);
    }
  }
  float hd_sum = block_reduce_256(s, smr, tid);

  {
    int img = tid >> 4, part = tid & 15;  // 16 threads per image
    float sp = 0.f, st = 0.f, spt = 0.f;
    for (int j = part; j < 64; j += 16) {  // 64 partials/image, 4 iters
      int idx = img * 64 + j;
      sp += spA[idx];
      st += stA[idx];
      spt += sptA[idx];
    }
#pragma unroll
    for (int off = 8; off > 0; off >>= 1) {
      sp += __shfl_down(sp, off, 16);
      st += __shfl_down(st, off, 16);
      spt += __shfl_down(spt, off, 16);
    }
    if (part == 0) {
      smImg[img][0] = sp;
      smImg[img][1] = st;
      smImg[img][2] = spt;
    }
  }
  __syncthreads();
  if (tid < 16) {
    double sp = smImg[tid][0], st = smImg[tid][1], spt = smImg[tid][2];
    double dice = (2.0 * spt + 1e-6) / (sp + st + 1e-6 + 1e-7);
    double tv = (spt + 1e-6) /
                (spt + 0.7 * (sp - spt) + 0.3 * (st - spt) + 1e-6 + 1e-7);
    smd[tid][0] = 1.0 - dice;
    smd[tid][1] = pow(1.0 - tv, 0.75);
  }
  __syncthreads();
  if (tid == 0) {
    double dice_l = 0.0, ft_l = 0.0;
    for (int i = 0; i < 16; ++i) {
      dice_l += smd[i][0];
      ft_l += smd[i][1];
    }
    dice_l /= 16.0;
    ft_l /= 16.0;
    const double Nd = (double)Nc;
    double bce = (double)bce_sum / Nd;
    double hd = ((double)hd_sum / Nd) / (5.5 + 1e-8);
    out[0] = (float)(bce + dice_l + ft_l + 0.1 * hd);
  }
}

}  // namespace

extern "C" void kernel_launch(void* const* d_in, const int* in_sizes, int n_in,
                              void* d_out, int out_size, void* d_ws,
                              size_t ws_size, hipStream_t stream) {
  const float* logits = (const float*)d_in[0];
  const int* target = (const int*)d_in[1];
  float* out = (float*)d_out;

  // Workspace: only small partial arrays (boundary maps never hit global).
  // All slots below are fully written each launch.
  float* part = (float*)d_ws;
  float* bceA = part;                  // 1024
  float* spA = part + NBCE;            // 1024
  float* stA = part + 2 * NBCE;        // 1024
  float* sptA = part + 3 * NBCE;       // 1024
  float* chain_p = part + 4 * NBCE;    // 6656 = 32*16*13 (16B aligned)

  fused_kernel<<<dim3(NBCE + NSB), dim3(256), 0, stream>>>(
      logits, target, bceA, spA, stA, sptA, chain_p);
  finalize_kernel<<<1, 256, 0, stream>>>(bceA, spA, stA, sptA, chain_p, out);
}